// Round 8
// baseline (21.399 us; speedup 1.0000x reference)
//
#include <hip/hip_runtime.h>

// out[b,d] = sum_c w[b,c] * f[idx[b,c,0],d] * f[idx[b,c,1],d]   (w==0 -> padding, tail-contiguous)
// fallback: out[b,:] = f[target_nodes[b],:] when has_edge[b] <= 0
//
// Layout (round 7 = round 6 + masked y-gather elision):
//  - float4 per lane, 32-lane half-wave per row => one wave handles TWO rows
//  - branch-free counted loop + XCD contiguous-chunk swizzle (round 6 win)
//  - NEW: only card-3 combos [u,v] need a second gathered row. [t,a] combos use
//    the in-register f[t]; [a,a] combos reuse the x-gather. The y-gather is
//    issued under an exec-mask branch (uniform per half-wave), so masked-off
//    lanes generate NO cache-line requests -> ~33% fewer TA lines.

typedef float vfloat4 __attribute__((ext_vector_type(4)));

__global__ __launch_bounds__(256) void tmp_aggregate_kernel(
    const float*  __restrict__ features,      // [N, 128]
    const int*    __restrict__ target_nodes,  // [B]
    const int*    __restrict__ comb_idx,      // [B, cmax, 2]
    const float*  __restrict__ comb_w,        // [B, cmax]
    const float*  __restrict__ has_edge,      // [B]
    float*        __restrict__ out,           // [B, 128]
    int B, int cmax)
{
    // --- XCD-aware bijective swizzle (contiguous chunk per XCD) ---
    const int nwg = gridDim.x;
    const int xcd = blockIdx.x & 7;
    const int j   = blockIdx.x >> 3;
    const int q   = nwg >> 3, r = nwg & 7;
    const int lb  = (xcd < r ? xcd * (q + 1) : r * (q + 1) + (xcd - r) * q) + j;

    const int lane    = threadIdx.x & 63;
    const int wave    = __builtin_amdgcn_readfirstlane((int)(threadIdx.x >> 6));
    const int sub     = lane & 31;            // lane within half-wave
    const int half    = lane >> 5;            // 0 -> row b0, 1 -> row b1
    const int rowbase = (lb * 4 + wave) * 2;
    const int b       = rowbase + half;
    if (rowbase >= B) return;                 // B even; both rows valid together

    const vfloat4* __restrict__ f4 = (const vfloat4*)features;
    const long base = (long)b * cmax;

    // --- per-row live-combo count (w != 0), padding is tail-contiguous ---
    int cnt = 0;
    for (int c0 = 0; c0 < cmax; c0 += 32) {
        const int c = c0 + sub;
        const float w = (c < cmax) ? comb_w[base + c] : 0.0f;
        const unsigned long long m = __ballot(w != 0.0f);
        cnt += __popc((unsigned int)(m >> (half * 32)));
        const bool tail0 = ((unsigned int)(m      ) != 0xffffffffu);
        const bool tail1 = ((unsigned int)(m >> 32) != 0xffffffffu);
        if (tail0 && tail1) break;            // both rows found their tail
    }

    // wave-uniform loop bound = max over the two half-waves
    const int cnt_other = __shfl(cnt, lane ^ 32);
    const int loop_n = __builtin_amdgcn_readfirstlane(cnt > cnt_other ? cnt : cnt_other);

    const int tnode = target_nodes[b];
    const vfloat4 ft = f4[(long)tnode * 32 + sub];

    // --- main loop: 1 mandatory gather + exec-masked 2nd gather (card-3 only) ---
    vfloat4 acc = {0.f, 0.f, 0.f, 0.f};
    const int2* __restrict__ idx2 = (const int2*)comb_idx;

    #pragma unroll 4
    for (int c = 0; c < loop_n; ++c) {
        const float w  = comb_w[base + c];            // broadcast within half-wave
        const int2  ix = idx2[base + c];

        const bool xt    = (ix.x == tnode);
        const bool has_t = xt || (ix.y == tnode);
        const bool dup   = (ix.x == ix.y);
        const int  ai    = xt ? ix.y : ix.x;          // the guaranteed-gather index

        const vfloat4 x = f4[(long)ai * 32 + sub];

        vfloat4 y;
        if (!has_t && !dup) {                         // card-3 combo: real 2nd gather
            y = f4[(long)ix.y * 32 + sub];
        } else {                                      // [t,a] -> ft ; [a,a] -> x
            y.x = has_t ? ft.x : x.x;
            y.y = has_t ? ft.y : x.y;
            y.z = has_t ? ft.z : x.z;
            y.w = has_t ? ft.w : x.w;
        }

        acc.x = fmaf(w * x.x, y.x, acc.x);
        acc.y = fmaf(w * x.y, y.y, acc.y);
        acc.z = fmaf(w * x.z, y.z, acc.z);
        acc.w = fmaf(w * x.w, y.w, acc.w);
    }

    const bool fb = !(has_edge[b] > 0.f);
    acc.x = fb ? ft.x : acc.x;
    acc.y = fb ? ft.y : acc.y;
    acc.z = fb ? ft.z : acc.z;
    acc.w = fb ? ft.w : acc.w;

    __builtin_nontemporal_store(acc, &((vfloat4*)out)[(long)b * 32 + sub]);
}

extern "C" void kernel_launch(void* const* d_in, const int* in_sizes, int n_in,
                              void* d_out, int out_size, void* d_ws, size_t ws_size,
                              hipStream_t stream) {
    const float* features     = (const float*)d_in[0];
    const int*   target_nodes = (const int*)d_in[1];
    const int*   comb_idx     = (const int*)d_in[2];
    const float* comb_w       = (const float*)d_in[3];
    const float* has_edge     = (const float*)d_in[4];
    float*       out          = (float*)d_out;

    const int B    = in_sizes[1];                 // 16384
    const int cmax = in_sizes[2] / (B * 2);       // combos per row (padded)

    const int rows_per_block = 8;                 // 4 waves x 2 rows
    const int grid = (B + rows_per_block - 1) / rows_per_block;

    tmp_aggregate_kernel<<<grid, 256, 0, stream>>>(
        features, target_nodes, comb_idx, comb_w, has_edge, out, B, cmax);
}